// Round 14
// baseline (120.260 us; speedup 1.0000x reference)
//
#include <hip/hip_runtime.h>
#include <math.h>

#define TS   32
#define PT   36
#define NPIX 1024
#define DF   72      // real feature dim
#define KP   96      // padded K: 3 MFMA k-steps of 32
#define IMH  320
#define IMW  320
#define NTW  10
#define NTILE 100

// ws layout offsets unchanged from proven R3..R12 (Flo region unused)
#define F_UNITS_PER_TILE 12288           // 64 rt * 3 ks * 4 c * 16 rows
#define FHI_BYTES (NTILE * F_UNITS_PER_TILE * 16)   // 19,660,800
#define SQ_OFF    (2 * FHI_BYTES)                   // 39,321,600

#define K2LOG2E 2.0813689810056077f      // (log2 e)^2: exp(-sqrt(x)) = exp2(-sqrt(K2*x))

typedef __attribute__((ext_vector_type(8))) short bf16x8;   // MFMA A/B frag
typedef __attribute__((ext_vector_type(8))) unsigned short u16x8;
typedef __attribute__((ext_vector_type(4))) float f32x4;    // MFMA C/D

// ---------------- kernel A: feature build (RNE bf16) + sqf (R12 exact) ----
__global__ __launch_bounds__(256)
void nlm_feat_kernel(const float* __restrict__ img,
                     u16x8* __restrict__ Fhi, float* __restrict__ Sq)
{
    __shared__ float Ploc[3][6][36];   // padded rows [2p, 2p+6) of the tile
    __shared__ int   ofsl[KP];
    const int tid  = threadIdx.x;
    const int part = blockIdx.x;    // 0..15
    const int tile = blockIdx.y;
    const int by   = (tile / NTW) * TS;
    const int bx   = (tile % NTW) * TS;
    const float* Pf = &Ploc[0][0][0];

    for (int idx = tid; idx < 3 * 6 * 36; idx += 256) {
        int c   = idx / 216;
        int rem = idx - c * 216;
        int yl  = rem / 36;
        int x   = rem - yl * 36;
        int y   = 2 * part + yl;
        int iy  = min(max(y - 2, 0), TS - 1);
        int ix  = min(max(x - 2, 0), TS - 1);
        Ploc[c][yl][x] = img[(c * IMH + by + iy) * IMW + bx + ix];
    }
    if (tid < KP) {
        int k = tid, v = 0;
        if (k < DF) {
            int c = k / 24, o = k - c * 24;
            int kk = o + (o >= 12);
            int i = kk / 5, j = kk - (kk / 5) * 5;
            v = c * 216 + i * 36 + j;
        }
        ofsl[k] = v;
    }
    __syncthreads();

    if (tid < 64) {
        int m  = part * 64 + tid;
        int my = m >> 5, mx = m & 31;
        int ly0 = my - 2 * part;
        float s = 0.f;
        #pragma unroll
        for (int k = 0; k < 25; ++k) {
            if (k == 12) continue;
            int i = k / 5, j = k - (k / 5) * 5;
            float v0 = Ploc[0][ly0 + i][mx + j];
            float v1 = Ploc[1][ly0 + i][mx + j];
            float v2 = Ploc[2][ly0 + i][mx + j];
            s = fmaf(v0, v0, s); s = fmaf(v1, v1, s); s = fmaf(v2, v2, s);
        }
        Sq[tile * NPIX + m] = s;
    }

    #pragma unroll
    for (int q = 0; q < 3; ++q) {
        int u    = part * 768 + q * 256 + tid;
        int row  = u & 15;
        int c4   = (u >> 4) & 3;
        int rks  = u >> 6;
        int ks   = rks - (rks / 3) * 3;
        int rt   = rks / 3;
        int r    = rt * 16 + row;
        int lbase = ((r >> 5) - 2 * part) * 36 + (r & 31);
        u16x8 h;
        #pragma unroll
        for (int j = 0; j < 8; ++j) {
            int k = ks * 32 + c4 * 8 + j;
            unsigned short hs = 0;
            if (k < DF) {
                float f = Pf[lbase + ofsl[k]];
                unsigned int uu = __float_as_uint(f);
                // round-to-nearest-even bf16
                hs = (unsigned short)((uu + 0x7fffu + ((uu >> 16) & 1u)) >> 16);
            }
            h[j] = hs;
        }
        Fhi[tile * F_UNITS_PER_TILE + u] = h;
    }
}

// ---------------- kernel B: single-bf16 MFMA GEMM (R12 exact data path) ---
// grid (32, 100): block owns 32 rows (2 row-tiles); wave wv sweeps 16 mt.
// R14 delta vs R12: waves_per_eu(2) min-only — the (2,3) max cap was the
// occupancy limiter (26% at only 72 VGPRs). A-frag remat blocked by asm pin.
// y/sq read from img/raw Sq: the ws-float4 My repack failed twice (R4/R13).
__global__ __launch_bounds__(256)
__attribute__((amdgpu_waves_per_eu(2)))
void nlm_gemm_kernel(const float* __restrict__ img,
                     const bf16x8* __restrict__ Fhi,
                     const float* __restrict__ Sq, float* __restrict__ out)
{
    __shared__ float red[4][32][4];
    const int tid  = threadIdx.x;
    const int lane = tid & 63;
    const int wv   = tid >> 6;
    const int tile = blockIdx.y;
    const int by   = (tile / NTW) * TS;
    const int bx   = (tile % NTW) * TS;
    const int rtA  = blockIdx.x * 2;
    const int quad = lane >> 4;
    const int col  = lane & 15;

    const bf16x8* FHt = Fhi + tile * F_UNITS_PER_TILE;
    const float*  Sqt = Sq + tile * NPIX;

    // A fragments — loaded once, pinned
    bf16x8 aH[2][3];
    #pragma unroll
    for (int t = 0; t < 2; ++t)
        #pragma unroll
        for (int ks = 0; ks < 3; ++ks)
            aH[t][ks] = FHt[((rtA + t) * 3 + ks) * 64 + lane];
    asm volatile(""
        : "+v"(aH[0][0]), "+v"(aH[0][1]), "+v"(aH[0][2]),
          "+v"(aH[1][0]), "+v"(aH[1][1]), "+v"(aH[1][2]));

    // sqn pre-scaled by K2: s2 = sqnK + smK - 2*K2*C
    float sqnK[2][4];
    #pragma unroll
    for (int t = 0; t < 2; ++t)
        #pragma unroll
        for (int i = 0; i < 4; ++i)
            sqnK[t][i] = Sqt[(rtA + t) * 16 + quad * 4 + i] * K2LOG2E;

    float rowsum[2][4] = {};
    float oacc[2][4][3] = {};

    #pragma unroll 2
    for (int it = 0; it < 16; ++it) {
        const int mt = wv * 16 + it;
        bf16x8 bH[3];
        #pragma unroll
        for (int ks = 0; ks < 3; ++ks)
            bH[ks] = FHt[(mt * 3 + ks) * 64 + lane];
        const int m  = mt * 16 + col;
        float smK = Sqt[m] * K2LOG2E;
        int my = m >> 5, mx = m & 31;
        float y0 = img[(0 * IMH + by + my) * IMW + bx + mx];
        float y1 = img[(1 * IMH + by + my) * IMW + bx + mx];
        float y2 = img[(2 * IMH + by + my) * IMW + bx + mx];

        f32x4 C0 = {0.f, 0.f, 0.f, 0.f};
        f32x4 C1 = {0.f, 0.f, 0.f, 0.f};
        #pragma unroll
        for (int ks = 0; ks < 3; ++ks) {
            C0 = __builtin_amdgcn_mfma_f32_16x16x32_bf16(aH[0][ks], bH[ks], C0, 0, 0, 0);
            C1 = __builtin_amdgcn_mfma_f32_16x16x32_bf16(aH[1][ks], bH[ks], C1, 0, 0, 0);
        }
        #pragma unroll
        for (int t = 0; t < 2; ++t) {
            f32x4 C = t ? C1 : C0;
            int nb = (rtA + t) * 16 + quad * 4;
            #pragma unroll
            for (int i = 0; i < 4; ++i) {
                float s2   = fmaxf(fmaf(-2.0f * K2LOG2E, C[i], sqnK[t][i] + smK), 0.f);
                float dens = __builtin_amdgcn_exp2f(-__builtin_amdgcn_sqrtf(s2));
                if (m == nb + i) dens = 0.f;
                rowsum[t][i] += dens;
                oacc[t][i][0] = fmaf(dens, y0, oacc[t][i][0]);
                oacc[t][i][1] = fmaf(dens, y1, oacc[t][i][1]);
                oacc[t][i][2] = fmaf(dens, y2, oacc[t][i][2]);
            }
        }
    }

    // in-wave reduce over the 16 column lanes
    #pragma unroll
    for (int mask = 1; mask < 16; mask <<= 1)
        #pragma unroll
        for (int t = 0; t < 2; ++t)
            #pragma unroll
            for (int i = 0; i < 4; ++i) {
                rowsum[t][i]  += __shfl_xor(rowsum[t][i],  mask, 64);
                oacc[t][i][0] += __shfl_xor(oacc[t][i][0], mask, 64);
                oacc[t][i][1] += __shfl_xor(oacc[t][i][1], mask, 64);
                oacc[t][i][2] += __shfl_xor(oacc[t][i][2], mask, 64);
            }

    if (col == 0) {
        #pragma unroll
        for (int t = 0; t < 2; ++t)
            #pragma unroll
            for (int i = 0; i < 4; ++i) {
                int lr = t * 16 + quad * 4 + i;
                red[wv][lr][0] = rowsum[t][i];
                red[wv][lr][1] = oacc[t][i][0];
                red[wv][lr][2] = oacc[t][i][1];
                red[wv][lr][3] = oacc[t][i][2];
            }
    }
    __syncthreads();

    if (tid < 32) {
        float s = 0.f, o0 = 0.f, o1 = 0.f, o2 = 0.f;
        #pragma unroll
        for (int w = 0; w < 4; ++w) {
            s  += red[w][tid][0];
            o0 += red[w][tid][1];
            o1 += red[w][tid][2];
            o2 += red[w][tid][3];
        }
        int n = rtA * 16 + tid;
        float inv = 1.f / s;
        int gy = by + (n >> 5), gx = bx + (n & 31);
        out[(0 * IMH + gy) * IMW + gx] = o0 * inv;
        out[(1 * IMH + gy) * IMW + gx] = o1 * inv;
        out[(2 * IMH + gy) * IMW + gx] = o2 * inv;
    }
}

extern "C" void kernel_launch(void* const* d_in, const int* in_sizes, int n_in,
                              void* d_out, int out_size, void* d_ws, size_t ws_size,
                              hipStream_t stream) {
    const float* img = (const float*)d_in[0];
    float* out = (float*)d_out;
    char* ws = (char*)d_ws;
    u16x8* Fhi = (u16x8*)ws;
    float* Sq  = (float*)(ws + SQ_OFF);

    dim3 fgrid(16, NTILE);
    nlm_feat_kernel<<<fgrid, 256, 0, stream>>>(img, Fhi, Sq);
    dim3 grid(32, NTILE);
    nlm_gemm_kernel<<<grid, 256, 0, stream>>>(img, (const bf16x8*)Fhi, Sq, out);
}

// Round 16
// 116.331 us; speedup vs baseline: 1.0338x; 1.0338x over previous
//
#include <hip/hip_runtime.h>
#include <math.h>

#define TS   32
#define PT   36
#define NPIX 1024
#define DF   72      // real feature dim
#define KP   96      // padded K: 3 MFMA k-steps of 32
#define IMH  320
#define IMW  320
#define NTW  10
#define NTILE 100

// ws layout offsets unchanged from proven R3..R12 (Flo region unused)
#define F_UNITS_PER_TILE 12288           // 64 rt * 3 ks * 4 c * 16 rows
#define FHI_BYTES (NTILE * F_UNITS_PER_TILE * 16)   // 19,660,800
#define SQ_OFF    (2 * FHI_BYTES)                   // 39,321,600

#define K2LOG2E 2.0813689810056077f      // (log2 e)^2: exp(-sqrt(x)) = exp2(-sqrt(K2*x))

typedef __attribute__((ext_vector_type(8))) short bf16x8;   // MFMA A/B frag
typedef __attribute__((ext_vector_type(8))) unsigned short u16x8;
typedef __attribute__((ext_vector_type(4))) float f32x4;    // MFMA C/D

// ---------------- kernel A: feature build, one thread per pixel -----------
// grid (4, 100): part covers 8 pixel-rows (256 pixels). All patch offsets
// are compile-time immediates (no ofsl LDS table, no dependent-load chain).
// RNE bf16 conversion done ONCE per staged value; Sq computed from the same
// fp32 values in R12's accumulation order -> outputs bit-identical to R12.
__global__ __launch_bounds__(256)
void nlm_feat_kernel(const float* __restrict__ img,
                     u16x8* __restrict__ Fhi, float* __restrict__ Sq)
{
    __shared__ float          Pf32[3][12][36];   // fp32 padded rows (Sq)
    __shared__ unsigned short Pb16[3][12][36];   // RNE bf16 (features)
    const int tid  = threadIdx.x;
    const int part = blockIdx.x;    // 0..3
    const int tile = blockIdx.y;
    const int by   = (tile / NTW) * TS;
    const int bx   = (tile % NTW) * TS;

    // stage padded rows y in [8p, 8p+12), x in [0,36), 3 channels
    for (int idx = tid; idx < 3 * 12 * 36; idx += 256) {
        int c   = idx / 432;
        int rem = idx - c * 432;
        int yl  = rem / 36;
        int x   = rem - yl * 36;
        int y   = 8 * part + yl;
        int iy  = min(max(y - 2, 0), TS - 1);
        int ix  = min(max(x - 2, 0), TS - 1);
        float f = img[(c * IMH + by + iy) * IMW + bx + ix];
        Pf32[c][yl][x] = f;
        unsigned int uu = __float_as_uint(f);
        Pb16[c][yl][x] = (unsigned short)((uu + 0x7fffu + ((uu >> 16) & 1u)) >> 16);
    }
    __syncthreads();

    const int m    = part * 256 + tid;   // this thread's pixel
    const int mx   = m & 31;
    const int ly   = (m >> 5) - 8 * part;        // 0..7
    const int base = ly * 36 + mx;
    const float*          Pfl = &Pf32[0][0][0];
    const unsigned short* Pbl = &Pb16[0][0][0];

    // Sq: same accumulation order as R12 (kk outer, c inner)
    {
        float s = 0.f;
        #pragma unroll
        for (int kk = 0; kk < 25; ++kk) {
            if (kk == 12) continue;
            int i = kk / 5, jo = kk - (kk / 5) * 5;
            float v0 = Pfl[base + 0 * 432 + i * 36 + jo];
            float v1 = Pfl[base + 1 * 432 + i * 36 + jo];
            float v2 = Pfl[base + 2 * 432 + i * 36 + jo];
            s = fmaf(v0, v0, s); s = fmaf(v1, v1, s); s = fmaf(v2, v2, s);
        }
        Sq[tile * NPIX + m] = s;
    }

    // features: 12 fragment units for this pixel, all offsets immediate
    const int rt = m >> 4, row = m & 15;
    #pragma unroll
    for (int ks = 0; ks < 3; ++ks) {
        #pragma unroll
        for (int c4 = 0; c4 < 4; ++c4) {
            u16x8 h;
            #pragma unroll
            for (int j = 0; j < 8; ++j) {
                const int k = ks * 32 + c4 * 8 + j;
                unsigned short hs = 0;
                if (k < DF) {
                    const int c  = k / 24;
                    const int o  = k - c * 24;
                    const int kk = o + (o >= 12);
                    const int i  = kk / 5, jo = kk - (kk / 5) * 5;
                    hs = Pbl[base + c * 432 + i * 36 + jo];
                }
                h[j] = hs;
            }
            Fhi[tile * F_UNITS_PER_TILE + (rt * 3 + ks) * 64 + c4 * 16 + row] = h;
        }
    }
}

// ---------------- kernel B: single-bf16 MFMA GEMM (R12 EXACT) -------------
// grid (32, 100): block owns 32 rows (2 row-tiles); wave wv sweeps 16 mt.
// Proven at 61 us / absmax 0.0039. Scalar img/Sq epilogue loads — every
// packed-(sq,y)-float4 variant (R4/R13/R15) failed; do not touch this loop.
__global__ __launch_bounds__(256)
__attribute__((amdgpu_waves_per_eu(2, 3)))
void nlm_gemm_kernel(const float* __restrict__ img,
                     const bf16x8* __restrict__ Fhi,
                     const float* __restrict__ Sq, float* __restrict__ out)
{
    __shared__ float red[4][32][4];
    const int tid  = threadIdx.x;
    const int lane = tid & 63;
    const int wv   = tid >> 6;
    const int tile = blockIdx.y;
    const int by   = (tile / NTW) * TS;
    const int bx   = (tile % NTW) * TS;
    const int rtA  = blockIdx.x * 2;
    const int quad = lane >> 4;
    const int col  = lane & 15;

    const bf16x8* FHt = Fhi + tile * F_UNITS_PER_TILE;
    const float*  Sqt = Sq + tile * NPIX;

    // A fragments — loaded once, pinned
    bf16x8 aH[2][3];
    #pragma unroll
    for (int t = 0; t < 2; ++t)
        #pragma unroll
        for (int ks = 0; ks < 3; ++ks)
            aH[t][ks] = FHt[((rtA + t) * 3 + ks) * 64 + lane];
    asm volatile(""
        : "+v"(aH[0][0]), "+v"(aH[0][1]), "+v"(aH[0][2]),
          "+v"(aH[1][0]), "+v"(aH[1][1]), "+v"(aH[1][2]));

    // sqn pre-scaled by K2: s2 = sqnK + smK - 2*K2*C
    float sqnK[2][4];
    #pragma unroll
    for (int t = 0; t < 2; ++t)
        #pragma unroll
        for (int i = 0; i < 4; ++i)
            sqnK[t][i] = Sqt[(rtA + t) * 16 + quad * 4 + i] * K2LOG2E;

    float rowsum[2][4] = {};
    float oacc[2][4][3] = {};

    #pragma unroll 2
    for (int it = 0; it < 16; ++it) {
        const int mt = wv * 16 + it;
        bf16x8 bH[3];
        #pragma unroll
        for (int ks = 0; ks < 3; ++ks)
            bH[ks] = FHt[(mt * 3 + ks) * 64 + lane];
        const int m  = mt * 16 + col;
        float smK = Sqt[m] * K2LOG2E;
        int my = m >> 5, mx = m & 31;
        float y0 = img[(0 * IMH + by + my) * IMW + bx + mx];
        float y1 = img[(1 * IMH + by + my) * IMW + bx + mx];
        float y2 = img[(2 * IMH + by + my) * IMW + bx + mx];

        f32x4 C0 = {0.f, 0.f, 0.f, 0.f};
        f32x4 C1 = {0.f, 0.f, 0.f, 0.f};
        #pragma unroll
        for (int ks = 0; ks < 3; ++ks) {
            C0 = __builtin_amdgcn_mfma_f32_16x16x32_bf16(aH[0][ks], bH[ks], C0, 0, 0, 0);
            C1 = __builtin_amdgcn_mfma_f32_16x16x32_bf16(aH[1][ks], bH[ks], C1, 0, 0, 0);
        }
        #pragma unroll
        for (int t = 0; t < 2; ++t) {
            f32x4 C = t ? C1 : C0;
            int nb = (rtA + t) * 16 + quad * 4;
            #pragma unroll
            for (int i = 0; i < 4; ++i) {
                float s2   = fmaxf(fmaf(-2.0f * K2LOG2E, C[i], sqnK[t][i] + smK), 0.f);
                float dens = __builtin_amdgcn_exp2f(-__builtin_amdgcn_sqrtf(s2));
                if (m == nb + i) dens = 0.f;
                rowsum[t][i] += dens;
                oacc[t][i][0] = fmaf(dens, y0, oacc[t][i][0]);
                oacc[t][i][1] = fmaf(dens, y1, oacc[t][i][1]);
                oacc[t][i][2] = fmaf(dens, y2, oacc[t][i][2]);
            }
        }
    }

    // in-wave reduce over the 16 column lanes
    #pragma unroll
    for (int mask = 1; mask < 16; mask <<= 1)
        #pragma unroll
        for (int t = 0; t < 2; ++t)
            #pragma unroll
            for (int i = 0; i < 4; ++i) {
                rowsum[t][i]  += __shfl_xor(rowsum[t][i],  mask, 64);
                oacc[t][i][0] += __shfl_xor(oacc[t][i][0], mask, 64);
                oacc[t][i][1] += __shfl_xor(oacc[t][i][1], mask, 64);
                oacc[t][i][2] += __shfl_xor(oacc[t][i][2], mask, 64);
            }

    if (col == 0) {
        #pragma unroll
        for (int t = 0; t < 2; ++t)
            #pragma unroll
            for (int i = 0; i < 4; ++i) {
                int lr = t * 16 + quad * 4 + i;
                red[wv][lr][0] = rowsum[t][i];
                red[wv][lr][1] = oacc[t][i][0];
                red[wv][lr][2] = oacc[t][i][1];
                red[wv][lr][3] = oacc[t][i][2];
            }
    }
    __syncthreads();

    if (tid < 32) {
        float s = 0.f, o0 = 0.f, o1 = 0.f, o2 = 0.f;
        #pragma unroll
        for (int w = 0; w < 4; ++w) {
            s  += red[w][tid][0];
            o0 += red[w][tid][1];
            o1 += red[w][tid][2];
            o2 += red[w][tid][3];
        }
        int n = rtA * 16 + tid;
        float inv = 1.f / s;
        int gy = by + (n >> 5), gx = bx + (n & 31);
        out[(0 * IMH + gy) * IMW + gx] = o0 * inv;
        out[(1 * IMH + gy) * IMW + gx] = o1 * inv;
        out[(2 * IMH + gy) * IMW + gx] = o2 * inv;
    }
}

extern "C" void kernel_launch(void* const* d_in, const int* in_sizes, int n_in,
                              void* d_out, int out_size, void* d_ws, size_t ws_size,
                              hipStream_t stream) {
    const float* img = (const float*)d_in[0];
    float* out = (float*)d_out;
    char* ws = (char*)d_ws;
    u16x8* Fhi = (u16x8*)ws;
    float* Sq  = (float*)(ws + SQ_OFF);

    dim3 fgrid(4, NTILE);
    nlm_feat_kernel<<<fgrid, 256, 0, stream>>>(img, Fhi, Sq);
    dim3 grid(32, NTILE);
    nlm_gemm_kernel<<<grid, 256, 0, stream>>>(img, (const bf16x8*)Fhi, Sq, out);
}